// Round 5
// baseline (295.120 us; speedup 1.0000x reference)
//
#include <hip/hip_runtime.h>
#include <cstdint>
#include <cstddef>

// ---------------- problem constants ----------------
#define BB 4
#define SS 2048
#define EE 512
#define HH 8
#define DD 64
#define MM (BB*SS)                       // 8192 token rows
#define BHSD ((size_t)BB*HH*SS*DD)       // 4194304 elements per q/k/v head tensor

static constexpr float SCALE_INV = 1.0f / 181.0f;   // SCALE = float(512 // 8**0.5) = 181.0
static constexpr float LN_EPS = 1e-5f;

typedef float  v4f  __attribute__((ext_vector_type(4)));
typedef __bf16 v8bf __attribute__((ext_vector_type(8)));
typedef __bf16 v4bf __attribute__((ext_vector_type(4)));

static __device__ __forceinline__ v4f mfma16(v8bf a, v8bf b, v4f c) {
  return __builtin_amdgcn_mfma_f32_16x16x32_bf16(a, b, c, 0, 0, 0);
}
// K=16 bf16 MFMA via inline asm (ISA §10: v_mfma_f32_16x16x16_bf16, A/B = 2 VGPRs).
// A-frag: row=l15, k=4*lg+0..3 ; B-frag: col=l15, k=4*lg+0..3 ; C/D: col=l15,row=4lg+reg.
static __device__ __forceinline__ v4f mfma16x16(v4bf a, v4bf b, v4f c) {
  v4f d;
  asm("v_mfma_f32_16x16x16_bf16 %0, %1, %2, %3" : "=&v"(d) : "v"(a), "v"(b), "v"(c));
  return d;
}

// ---------------- workspace layout (bytes) ----------------
// Xb  bf16 [3][M][E]       : 25165824   (q,k,v inputs as bf16)
// Wb  bf16 [4][E][E]       :  2097152   (Wq,Wk,Wv,Wo as bf16)
// Xh  bf16: q [B][H][S][D], k [B][H][S][D], vT [B][H][D][S]   : 25165824
// AO  bf16 [M][E]          :  8388608   (attention output, merged heads)
// maskF f32 [3][M]         :    98304
static constexpr size_t oXb = 0;
static constexpr size_t oWb = oXb + (size_t)3*MM*EE*2;
static constexpr size_t oXh = oWb + (size_t)4*EE*EE*2;
static constexpr size_t oAO = oXh + (size_t)3*MM*EE*2;
static constexpr size_t oMk = oAO + (size_t)MM*EE*2;

// ================= mask canonicalization =================
__global__ void mask_kernel(const void* qm, const void* km, const void* vm, float* maskF) {
  __shared__ int s_n01, s_nF;
  const int t = threadIdx.x;
  if (t == 0) { s_n01 = 0; s_nF = 0; }
  __syncthreads();
  int n01 = 0, nF = 0;
  const unsigned* wq = (const unsigned*)qm;
  for (int i = t; i < 2048; i += 256) {
    const unsigned u = wq[i];
    if (u != 0u && u != 1u) n01 = 1;
    if (u != 0u && u != 0x3F800000u) nF = 1;
  }
  if (n01) atomicOr(&s_n01, 1);
  if (nF)  atomicOr(&s_nF, 1);
  __syncthreads();
  const int mode = (!s_n01) ? 0 : (!s_nF) ? 1 : 2;   // 0=i32, 1=f32, 2=u8
  for (int m = 0; m < 3; ++m) {
    const void* p = (m == 0) ? qm : (m == 1) ? km : vm;
    for (int i = t; i < MM; i += 256) {
      int v;
      if (mode == 0)      v = (((const int*)p)[i] != 0);
      else if (mode == 1) v = (((const unsigned*)p)[i] != 0u);
      else                v = (((const unsigned char*)p)[i] != 0);
      maskF[m*MM + i] = v ? 1.0f : 0.0f;
    }
  }
}

// ================= fp32 -> bf16 convert =================
__global__ void convert_kernel(const float* q, const float* k, const float* v,
                               const float* Wq, const float* Wk, const float* Wv, const float* Wo,
                               __bf16* Xb, __bf16* Wb) {
  const long idx = (long)blockIdx.x * 256 + threadIdx.x;     // in float4 units
  const long NX4 = (long)3*MM*EE/4;
  const long NW4 = (long)4*EE*EE/4;
  if (idx < NX4) {
    const long per = (long)MM*EE/4;
    const long mat = idx / per, off = idx % per;
    const float* src = (mat == 0) ? q : (mat == 1) ? k : v;
    v4f val = ((const v4f*)src)[off];
    v4bf o; o[0]=(__bf16)val[0]; o[1]=(__bf16)val[1]; o[2]=(__bf16)val[2]; o[3]=(__bf16)val[3];
    ((v4bf*)Xb)[idx] = o;
  } else if (idx < NX4 + NW4) {
    const long j = idx - NX4;
    const long per = (long)EE*EE/4;
    const long mat = j / per, off = j % per;
    const float* src = (mat == 0) ? Wq : (mat == 1) ? Wk : (mat == 2) ? Wv : Wo;
    v4f val = ((const v4f*)src)[off];
    v4bf o; o[0]=(__bf16)val[0]; o[1]=(__bf16)val[1]; o[2]=(__bf16)val[2]; o[3]=(__bf16)val[3];
    ((v4bf*)Wb)[j] = o;
  }
}

// ===== projection GEMM + bias + mask + per-head LayerNorm, fused =====
// mat 0 (q), 1 (k): Xh region row-major [B][H][S][D].
// mat 2 (v): written TRANSPOSED per head: [B][H][D][S] (for barrier-free attn PV).
__global__ __launch_bounds__(256) void gemm_proj_ln(const __bf16* Xb, const __bf16* Wb,
                                                    const float* bq, const float* bk, const float* bv,
                                                    const float* gq, const float* betaq,
                                                    const float* gk, const float* betak,
                                                    const float* gv, const float* betav,
                                                    const float* maskF, __bf16* Xh) {
  const int m0  = blockIdx.x * 128;
  const int n0  = blockIdx.y * 128;
  const int mat = blockIdx.z;
  const __bf16* A = Xb + (size_t)mat*MM*EE;
  const __bf16* W = Wb + (size_t)mat*EE*EE;
  const float* bias = (mat == 0) ? bq : (mat == 1) ? bk : bv;
  const float* gam  = (mat == 0) ? gq : (mat == 1) ? gk : gv;
  const float* bet  = (mat == 0) ? betaq : (mat == 1) ? betak : betav;

  __shared__ __bf16 As[128*32];   // [row][k], 64B rows, 4-slot XOR swizzle
  __shared__ __bf16 Bs[128*32];

  const int t = threadIdx.x;
  const int lane = t & 63, w = t >> 6;
  const int wm = w >> 1, wn = w & 1;
  const int l15 = lane & 15, lg = lane >> 4;

  v4f acc[4][4];
  const v4f zf = {0.f, 0.f, 0.f, 0.f};
#pragma unroll
  for (int i = 0; i < 4; ++i)
#pragma unroll
    for (int j = 0; j < 4; ++j) acc[i][j] = zf;

  const int sr  = t >> 1;
  const int sc0 = (t & 1) * 2;

  for (int kt = 0; kt < EE; kt += 32) {
    const __bf16* ga = A + (size_t)(m0 + sr)*EE + kt + sc0*8;
    const __bf16* gb = W + (size_t)(n0 + sr)*EE + kt + sc0*8;
#pragma unroll
    for (int i = 0; i < 2; ++i) {
      const int c = sc0 + i;
      const int dst = sr*64 + ((c*16) ^ ((sr & 3) << 4));
      *(v8bf*)((char*)As + dst) = *(const v8bf*)((const char*)ga + i*16);
      *(v8bf*)((char*)Bs + dst) = *(const v8bf*)((const char*)gb + i*16);
    }
    __syncthreads();
    v8bf afr[4], bfr[4];
#pragma unroll
    for (int i = 0; i < 4; ++i) {
      const int ra = wm*64 + i*16 + l15;
      afr[i] = *(const v8bf*)((const char*)As + ra*64 + ((16*lg) ^ ((ra & 3) << 4)));
      const int rb = wn*64 + i*16 + l15;
      bfr[i] = *(const v8bf*)((const char*)Bs + rb*64 + ((16*lg) ^ ((rb & 3) << 4)));
    }
#pragma unroll
    for (int i = 0; i < 4; ++i)
#pragma unroll
      for (int j = 0; j < 4; ++j)
        acc[i][j] = mfma16(afr[i], bfr[j], acc[i][j]);
    __syncthreads();
  }

  // ---- fused epilogue: bias, mask, per-head LN, bf16 store ----
  const int nbase = n0 + wn*64;          // 64-aligned => one head
  const int h = nbase >> 6;
  float bsv[4], gmv[4], btv[4];
#pragma unroll
  for (int j = 0; j < 4; ++j) {
    const int d = j*16 + l15;
    bsv[j] = bias[nbase + d];
    gmv[j] = gam[d];
    btv[j] = bet[d];
  }
#pragma unroll
  for (int i = 0; i < 4; ++i)
#pragma unroll
    for (int rr = 0; rr < 4; ++rr) {
      const int row = m0 + wm*64 + i*16 + 4*lg + rr;
      const float mv = maskF[mat*MM + row];
      float x[4];
      float s = 0.f, s2 = 0.f;
#pragma unroll
      for (int j = 0; j < 4; ++j) {
        x[j] = (acc[i][j][rr] + bsv[j]) * mv;
        s += x[j]; s2 += x[j]*x[j];
      }
      s  += __shfl_xor(s, 1, 64);  s  += __shfl_xor(s, 2, 64);
      s  += __shfl_xor(s, 4, 64);  s  += __shfl_xor(s, 8, 64);
      s2 += __shfl_xor(s2, 1, 64); s2 += __shfl_xor(s2, 2, 64);
      s2 += __shfl_xor(s2, 4, 64); s2 += __shfl_xor(s2, 8, 64);
      const float mu  = s * (1.0f/64.0f);
      const float var = s2 * (1.0f/64.0f) - mu*mu;
      const float rstd = rsqrtf(var + LN_EPS);
      const int bidx = row >> 11, sI = row & 2047;
      if (mat == 2) {
        // V^T layout: [B][H][D][S]
        const size_t vbase = 2*BHSD + (((size_t)bidx*HH + h)*DD)*SS;
#pragma unroll
        for (int j = 0; j < 4; ++j)
          Xh[vbase + (size_t)(j*16 + l15)*SS + sI] = (__bf16)((x[j] - mu)*rstd*gmv[j] + btv[j]);
      } else {
        const size_t base = (size_t)mat*BHSD + (((size_t)bidx*HH + h)*SS + sI)*DD;
#pragma unroll
        for (int j = 0; j < 4; ++j)
          Xh[base + j*16 + l15] = (__bf16)((x[j] - mu)*rstd*gmv[j] + btv[j]);
      }
    }
}

// ================= flash attention, barrier-free / LDS-free =================
// grid (S/32, H, B); block = 1 wave (64 threads); wave owns 32 q rows.
// Swapped QK^T: S^T = mfma(K,Q) -> lane holds q=l15 scores, keys f*16+4lg+rr.
// That per-lane key layout IS the A-frag of v_mfma_f32_16x16x16_bf16, so PV
// needs no cross-lane traffic. V read from global V^T [B][H][D][S].
__global__ __launch_bounds__(64) void attn_kernel(const __bf16* Xh, const float* maskF, __bf16* AO) {
  const int qb = blockIdx.x, h = blockIdx.y, b = blockIdx.z;
  const int lane = threadIdx.x & 63;
  const int l15 = lane & 15, lg = lane >> 4;

  const size_t headoff = (((size_t)b*HH + h)*SS)*DD;
  const __bf16* Qg = Xh + headoff;
  const __bf16* Kg = Xh + BHSD + headoff;
  const __bf16* Vt = Xh + 2*BHSD + (((size_t)b*HH + h)*DD)*SS;   // [D][S]
  const float* qmF = maskF + (size_t)b*SS;
  const float* kmF = maskF + MM + (size_t)b*SS;

  const int q0 = qb*32;

  // Q fragments, pre-scaled by 1/181 (softmax shift-invariance makes this exact
  // up to bf16 rounding, same as ref's bf16-rounded inputs)
  v8bf qf[2][2];
#pragma unroll
  for (int m = 0; m < 2; ++m)
#pragma unroll
    for (int kd = 0; kd < 2; ++kd) {
      v8bf r = *(const v8bf*)(Qg + (size_t)(q0 + m*16 + l15)*DD + kd*32 + lg*8);
      v8bf o;
#pragma unroll
      for (int e = 0; e < 8; ++e) o[e] = (__bf16)((float)r[e] * SCALE_INV);
      qf[m][kd] = o;
    }

  v4f O[2][4];
  float mrun[2], lrun[2];
  const v4f zf = {0.f,0.f,0.f,0.f};
#pragma unroll
  for (int m = 0; m < 2; ++m) {
    mrun[m] = -INFINITY; lrun[m] = 0.f;
#pragma unroll
    for (int df = 0; df < 4; ++df) O[m][df] = zf;
  }

  for (int kt0 = 0; kt0 < SS; kt0 += 64) {
    // ---- loads for this tile (independent; compiler orders waits by first use) ----
    v8bf kf[4][2];
#pragma unroll
    for (int f = 0; f < 4; ++f)
#pragma unroll
      for (int kd = 0; kd < 2; ++kd)
        kf[f][kd] = *(const v8bf*)(Kg + (size_t)(kt0 + f*16 + l15)*DD + kd*32 + lg*8);
    v4bf vf[4][4];
#pragma unroll
    for (int f = 0; f < 4; ++f)
#pragma unroll
      for (int df = 0; df < 4; ++df)
        vf[f][df] = *(const v4bf*)(Vt + (size_t)(df*16 + l15)*SS + kt0 + f*16 + 4*lg);
    v4f km4[4];
#pragma unroll
    for (int f = 0; f < 4; ++f)
      km4[f] = *(const v4f*)(kmF + kt0 + f*16 + 4*lg);

    // ---- S^T = K Q^T : C[key][q], lane: q=l15, key=f*16+4*lg+rr ----
    v4f st[2][4];
#pragma unroll
    for (int m = 0; m < 2; ++m)
#pragma unroll
      for (int f = 0; f < 4; ++f) st[m][f] = zf;
#pragma unroll
    for (int kd = 0; kd < 2; ++kd)
#pragma unroll
      for (int f = 0; f < 4; ++f)
#pragma unroll
        for (int m = 0; m < 2; ++m)
          st[m][f] = mfma16(kf[f][kd], qf[m][kd], st[m][f]);

    // ---- online softmax, fully in-register ----
#pragma unroll
    for (int m = 0; m < 2; ++m) {
      float p[4][4];
      float pmax = -3e38f;
#pragma unroll
      for (int f = 0; f < 4; ++f)
#pragma unroll
        for (int rr = 0; rr < 4; ++rr) {
          const float sv = (km4[f][rr] > 0.5f) ? st[m][f][rr] : -1e9f;
          p[f][rr] = sv;
          pmax = fmaxf(pmax, sv);
        }
      pmax = fmaxf(pmax, __shfl_xor(pmax, 16, 64));
      pmax = fmaxf(pmax, __shfl_xor(pmax, 32, 64));
      const float mnew = fmaxf(mrun[m], pmax);
      const float corr = __expf(mrun[m] - mnew);
      mrun[m] = mnew;
      float lt = 0.f;
#pragma unroll
      for (int f = 0; f < 4; ++f)
#pragma unroll
        for (int rr = 0; rr < 4; ++rr) {
          const float e = __expf(p[f][rr] - mnew);
          p[f][rr] = e;
          lt += e;
        }
      lt += __shfl_xor(lt, 16, 64);
      lt += __shfl_xor(lt, 32, 64);
      lrun[m] = lrun[m]*corr + lt;
      // O rescale: O rows are q=4*lg+rr; stats live at q=l15 -> broadcast via shfl
#pragma unroll
      for (int rr = 0; rr < 4; ++rr) {
        const float corrO = __shfl(corr, (lg << 4) | (4*lg + rr), 64);
        O[m][0][rr] *= corrO; O[m][1][rr] *= corrO;
        O[m][2][rr] *= corrO; O[m][3][rr] *= corrO;
      }
      // ---- PV: P per-lane layout == 16x16x16 A-frag (k = 4*lg+0..3) ----
#pragma unroll
      for (int f = 0; f < 4; ++f) {
        v4bf pa;
        pa[0] = (__bf16)p[f][0]; pa[1] = (__bf16)p[f][1];
        pa[2] = (__bf16)p[f][2]; pa[3] = (__bf16)p[f][3];
#pragma unroll
        for (int df = 0; df < 4; ++df)
          O[m][df] = mfma16x16(pa, vf[f][df], O[m][df]);
      }
    }
  }

  // ---- epilogue: 1/l, query mask, store ----
#pragma unroll
  for (int m = 0; m < 2; ++m)
#pragma unroll
    for (int rr = 0; rr < 4; ++rr) {
      const float lr = __shfl(lrun[m], (lg << 4) | (4*lg + rr), 64);
      const int qrow = q0 + m*16 + 4*lg + rr;
      const float scl = qmF[qrow] / lr;
#pragma unroll
      for (int df = 0; df < 4; ++df)
        AO[(size_t)(b*SS + qrow)*EE + h*DD + df*16 + l15] = (__bf16)(O[m][df][rr] * scl);
    }
}

// ================= output GEMM: out = (AO @ Wo^T + bo) * qmask =================
__global__ __launch_bounds__(256) void gemm_out(const __bf16* AO, const __bf16* Wb,
                                                const float* bo, const float* maskF, float* out) {
  const int m0 = blockIdx.x * 128;
  const int n0 = blockIdx.y * 128;
  const __bf16* A = AO;
  const __bf16* W = Wb + (size_t)3*EE*EE;   // Wo

  __shared__ __bf16 As[128*32];
  __shared__ __bf16 Bs[128*32];

  const int t = threadIdx.x;
  const int lane = t & 63, w = t >> 6;
  const int wm = w >> 1, wn = w & 1;
  const int l15 = lane & 15, lg = lane >> 4;

  v4f acc[4][4];
  const v4f zf = {0.f,0.f,0.f,0.f};
#pragma unroll
  for (int i = 0; i < 4; ++i)
#pragma unroll
    for (int j = 0; j < 4; ++j) acc[i][j] = zf;

  const int sr  = t >> 1;
  const int sc0 = (t & 1) * 2;

  for (int kt = 0; kt < EE; kt += 32) {
    const __bf16* ga = A + (size_t)(m0 + sr)*EE + kt + sc0*8;
    const __bf16* gb = W + (size_t)(n0 + sr)*EE + kt + sc0*8;
#pragma unroll
    for (int i = 0; i < 2; ++i) {
      const int c = sc0 + i;
      const int dst = sr*64 + ((c*16) ^ ((sr & 3) << 4));
      *(v8bf*)((char*)As + dst) = *(const v8bf*)((const char*)ga + i*16);
      *(v8bf*)((char*)Bs + dst) = *(const v8bf*)((const char*)gb + i*16);
    }
    __syncthreads();
    v8bf afr[4], bfr[4];
#pragma unroll
    for (int i = 0; i < 4; ++i) {
      const int ra = wm*64 + i*16 + l15;
      afr[i] = *(const v8bf*)((const char*)As + ra*64 + ((16*lg) ^ ((ra & 3) << 4)));
      const int rb = wn*64 + i*16 + l15;
      bfr[i] = *(const v8bf*)((const char*)Bs + rb*64 + ((16*lg) ^ ((rb & 3) << 4)));
    }
#pragma unroll
    for (int i = 0; i < 4; ++i)
#pragma unroll
      for (int j = 0; j < 4; ++j)
        acc[i][j] = mfma16(afr[i], bfr[j], acc[i][j]);
    __syncthreads();
  }

  float bsv[4]; int ncol[4];
#pragma unroll
  for (int j = 0; j < 4; ++j) {
    ncol[j] = n0 + wn*64 + j*16 + l15;
    bsv[j] = bo[ncol[j]];
  }
#pragma unroll
  for (int i = 0; i < 4; ++i)
#pragma unroll
    for (int rr = 0; rr < 4; ++rr) {
      const int row = m0 + wm*64 + i*16 + 4*lg + rr;
      const float mv = maskF[row];   // query mask
#pragma unroll
      for (int j = 0; j < 4; ++j)
        out[(size_t)row*EE + ncol[j]] = (acc[i][j][rr] + bsv[j]) * mv;
    }
}

// ================= launcher =================
extern "C" void kernel_launch(void* const* d_in, const int* in_sizes, int n_in,
                              void* d_out, int out_size, void* d_ws, size_t ws_size,
                              hipStream_t stream) {
  const float* q  = (const float*)d_in[0];
  const float* k  = (const float*)d_in[1];
  const float* v  = (const float*)d_in[2];
  const float* Wq = (const float*)d_in[3];
  const float* bq = (const float*)d_in[4];
  const float* Wk = (const float*)d_in[5];
  const float* bk = (const float*)d_in[6];
  const float* Wv = (const float*)d_in[7];
  const float* bv = (const float*)d_in[8];
  const float* Wo = (const float*)d_in[9];
  const float* bo = (const float*)d_in[10];
  const float* gq = (const float*)d_in[11];
  const float* betaq = (const float*)d_in[12];
  const float* gk = (const float*)d_in[13];
  const float* betak = (const float*)d_in[14];
  const float* gv = (const float*)d_in[15];
  const float* betav = (const float*)d_in[16];

  char* ws = (char*)d_ws;
  __bf16* Xb = (__bf16*)(ws + oXb);
  __bf16* Wb = (__bf16*)(ws + oWb);
  __bf16* Xh = (__bf16*)(ws + oXh);
  __bf16* AO = (__bf16*)(ws + oAO);
  float*  maskF = (float*)(ws + oMk);

  mask_kernel<<<dim3(1), dim3(256), 0, stream>>>(d_in[17], d_in[18], d_in[19], maskF);
  convert_kernel<<<dim3(13312), dim3(256), 0, stream>>>(q, k, v, Wq, Wk, Wv, Wo, Xb, Wb);
  gemm_proj_ln<<<dim3(64, 4, 3), dim3(256), 0, stream>>>(Xb, Wb, bq, bk, bv,
                                                         gq, betaq, gk, betak, gv, betav,
                                                         maskF, Xh);
  attn_kernel<<<dim3(64, 8, 4), dim3(64), 0, stream>>>(Xh, maskF, AO);
  gemm_out<<<dim3(64, 4, 1), dim3(256), 0, stream>>>(AO, Wb, bo, maskF, (float*)d_out);
}